// Round 1
// baseline (399.097 us; speedup 1.0000x reference)
//
#include <hip/hip_runtime.h>
#include <math.h>

#define B_TOTAL 8192
#define C_DIM 62
#define D_DIM 8
#define EPSV 1e-4f
#define LSTRIDE 129   // 129 % 32 == 1 -> conflict-free per-lane LDS regions
#define NSWEEP 6

// ---------------- Kernel A: M1[b] = w1^T X[b] w1  (62->8) ----------------
__global__ __launch_bounds__(256) void bimap1_kernel(
    const float* __restrict__ X, const float* __restrict__ w1,
    float* __restrict__ M1) {
  __shared__ float Xs[C_DIM * C_DIM];
  __shared__ float w1s[C_DIM * D_DIM];
  __shared__ float Ys[C_DIM * D_DIM];
  const int b = blockIdx.x;
  const float* Xb = X + (size_t)b * (C_DIM * C_DIM);
  for (int i = threadIdx.x; i < C_DIM * C_DIM; i += 256) Xs[i] = Xb[i];
  for (int i = threadIdx.x; i < C_DIM * D_DIM; i += 256) w1s[i] = w1[i];
  __syncthreads();
  // Y[c][e] = sum_d X[c][d] * w1[d][e]
  for (int i = threadIdx.x; i < C_DIM * D_DIM; i += 256) {
    int c = i >> 3, e = i & 7;
    float acc = 0.f;
#pragma unroll
    for (int d = 0; d < C_DIM; ++d)
      acc = fmaf(Xs[c * C_DIM + d], w1s[d * D_DIM + e], acc);
    Ys[i] = acc;
  }
  __syncthreads();
  // M1[a][e] = sum_c w1[c][a] * Y[c][e]
  if (threadIdx.x < 64) {
    int a = threadIdx.x >> 3, e = threadIdx.x & 7;
    float acc = 0.f;
#pragma unroll
    for (int c = 0; c < C_DIM; ++c)
      acc = fmaf(w1s[c * D_DIM + a], Ys[c * D_DIM + e], acc);
    M1[(size_t)b * 64 + threadIdx.x] = acc;
  }
}

// ---------------- Kernel B: per-batch Jacobi eig pipeline ----------------
__device__ __forceinline__ void jacobi8(float* Ap, float* Up) {
  // U = I
#pragma unroll
  for (int i = 0; i < 64; ++i) Up[i] = 0.f;
#pragma unroll
  for (int i = 0; i < 8; ++i) Up[i * 8 + i] = 1.f;
#pragma unroll 1
  for (int sweep = 0; sweep < NSWEEP; ++sweep) {
#pragma unroll 1
    for (int p = 0; p < 7; ++p) {
#pragma unroll 1
      for (int q = p + 1; q < 8; ++q) {
        float app = Ap[p * 8 + p];
        float aqq = Ap[q * 8 + q];
        float apq = Ap[p * 8 + q];
        float taun = aqq - app;
        float t = (2.f * apq) * copysignf(1.f, taun) /
                  (fabsf(taun) + sqrtf(taun * taun + 4.f * apq * apq) + 1e-38f);
        float c = 1.f / sqrtf(1.f + t * t);
        float s = t * c;
        // rows p,q :  A <- J^T A
#pragma unroll
        for (int j = 0; j < 8; ++j) {
          float x = Ap[p * 8 + j], y = Ap[q * 8 + j];
          Ap[p * 8 + j] = c * x - s * y;
          Ap[q * 8 + j] = s * x + c * y;
        }
        // cols p,q :  A <- A J
#pragma unroll
        for (int i = 0; i < 8; ++i) {
          float x = Ap[i * 8 + p], y = Ap[i * 8 + q];
          Ap[i * 8 + p] = c * x - s * y;
          Ap[i * 8 + q] = s * x + c * y;
        }
        // U <- U J
#pragma unroll
        for (int i = 0; i < 8; ++i) {
          float x = Up[i * 8 + p], y = Up[i * 8 + q];
          Up[i * 8 + p] = c * x - s * y;
          Up[i * 8 + q] = s * x + c * y;
        }
      }
    }
  }
}

__global__ __launch_bounds__(64) void spd_eig_kernel(
    const float* __restrict__ M1, const float* __restrict__ w2,
    const float* __restrict__ fc, float* __restrict__ out) {
  __shared__ float lds[64 * LSTRIDE];
  __shared__ float w2s[64];
  __shared__ float fcs[128];
  const int lane = threadIdx.x;
  const int b = blockIdx.x * 64 + lane;
  w2s[lane] = w2[lane];
  fcs[lane] = fc[lane];
  fcs[lane + 64] = fc[lane + 64];
  float* Ap = &lds[lane * LSTRIDE];
  float* Up = Ap + 64;
  // load M1[b] (per-thread contiguous, float4)
  const float4* m4 = (const float4*)(M1 + (size_t)b * 64);
#pragma unroll
  for (int i = 0; i < 16; ++i) {
    float4 v = m4[i];
    Ap[i * 4 + 0] = v.x; Ap[i * 4 + 1] = v.y;
    Ap[i * 4 + 2] = v.z; Ap[i * 4 + 3] = v.w;
  }
  __syncthreads();

  // ---- eig 1 + rec (fused into M2 formation) ----
  jacobi8(Ap, Up);
  float wc[8];
#pragma unroll
  for (int k = 0; k < 8; ++k) wc[k] = fmaxf(Ap[k * 8 + k], EPSV);
  // V = U^T w2  -> store into A region (A no longer needed)
#pragma unroll
  for (int k = 0; k < 8; ++k) {
    float vk[8];
#pragma unroll
    for (int e = 0; e < 8; ++e) {
      float acc = 0.f;
#pragma unroll
      for (int i = 0; i < 8; ++i)
        acc = fmaf(Up[i * 8 + k], w2s[i * 8 + e], acc);
      vk[e] = acc;
    }
#pragma unroll
    for (int e = 0; e < 8; ++e) Ap[k * 8 + e] = vk[e];
  }
  // M2[a][e] = sum_k V[k][a] * wc[k] * V[k][e]  -> into U region (scratch)
#pragma unroll
  for (int a = 0; a < 8; ++a) {
    float row[8];
#pragma unroll
    for (int e = 0; e < 8; ++e) {
      float acc = 0.f;
#pragma unroll
      for (int k = 0; k < 8; ++k)
        acc = fmaf(Ap[k * 8 + a] * wc[k], Ap[k * 8 + e], acc);
      row[e] = acc;
    }
#pragma unroll
    for (int e = 0; e < 8; ++e) Up[a * 8 + e] = row[e];
  }
  // move M2 into A region
#pragma unroll
  for (int i = 0; i < 64; ++i) Ap[i] = Up[i];

  // ---- eig 2 + fused rec+logm ----
  jacobi8(Ap, Up);
  float lw[8];
#pragma unroll
  for (int k = 0; k < 8; ++k) lw[k] = logf(fmaxf(Ap[k * 8 + k], EPSV));

  // feat[i][j] = sum_k U[i][k] * lw[k] * U[j][k];  logits = feat @ fc
  float l0 = 0.f, l1 = 0.f;
  float* featg = out + 2 * (size_t)B_TOTAL + (size_t)b * 64;
#pragma unroll
  for (int i = 0; i < 8; ++i) {
#pragma unroll
    for (int j = 0; j < 8; ++j) {
      float acc = 0.f;
#pragma unroll
      for (int k = 0; k < 8; ++k)
        acc = fmaf(Up[i * 8 + k] * lw[k], Up[j * 8 + k], acc);
      featg[i * 8 + j] = acc;
      l0 = fmaf(acc, fcs[(i * 8 + j) * 2 + 0], l0);
      l1 = fmaf(acc, fcs[(i * 8 + j) * 2 + 1], l1);
    }
  }
  float mx = fmaxf(l0, l1);
  float lse = mx + logf(expf(l0 - mx) + expf(l1 - mx));
  out[(size_t)b * 2 + 0] = l0 - lse;
  out[(size_t)b * 2 + 1] = l1 - lse;
}

extern "C" void kernel_launch(void* const* d_in, const int* in_sizes, int n_in,
                              void* d_out, int out_size, void* d_ws, size_t ws_size,
                              hipStream_t stream) {
  const float* X  = (const float*)d_in[0];   // [8192,62,62]
  const float* w1 = (const float*)d_in[1];   // [62,8]
  const float* w2 = (const float*)d_in[2];   // [8,8]
  const float* fc = (const float*)d_in[3];   // [64,2]
  float* out = (float*)d_out;                // [8192*2] ++ [8192*64]
  float* M1 = (float*)d_ws;                  // 8192*64 floats = 2 MB

  bimap1_kernel<<<B_TOTAL, 256, 0, stream>>>(X, w1, M1);
  spd_eig_kernel<<<B_TOTAL / 64, 64, 0, stream>>>(M1, w2, fc, out);
}

// Round 2
// 164.958 us; speedup vs baseline: 2.4194x; 2.4194x over previous
//
#include <hip/hip_runtime.h>
#include <math.h>

#define B_TOTAL 8192
#define C_DIM 62
#define D_DIM 8
#define EPSV 1e-4f
#define NSWEEP 6

// ---------------- Kernel A: M1[b] = w1^T X[b] w1  (62->8) ----------------
__global__ __launch_bounds__(256) void bimap1_kernel(
    const float* __restrict__ X, const float* __restrict__ w1,
    float* __restrict__ M1) {
  __shared__ float Xs[C_DIM * C_DIM];
  __shared__ float w1s[C_DIM * D_DIM];
  __shared__ float Ys[C_DIM * D_DIM];
  const int b = blockIdx.x;
  const float* Xb = X + (size_t)b * (C_DIM * C_DIM);
  for (int i = threadIdx.x; i < C_DIM * C_DIM; i += 256) Xs[i] = Xb[i];
  for (int i = threadIdx.x; i < C_DIM * D_DIM; i += 256) w1s[i] = w1[i];
  __syncthreads();
  // Y[c][e] = sum_d X[c][d] * w1[d][e]
  for (int i = threadIdx.x; i < C_DIM * D_DIM; i += 256) {
    int c = i >> 3, e = i & 7;
    float acc = 0.f;
#pragma unroll
    for (int d = 0; d < C_DIM; ++d)
      acc = fmaf(Xs[c * C_DIM + d], w1s[d * D_DIM + e], acc);
    Ys[i] = acc;
  }
  __syncthreads();
  // M1[a][e] = sum_c w1[c][a] * Y[c][e]
  if (threadIdx.x < 64) {
    int a = threadIdx.x >> 3, e = threadIdx.x & 7;
    float acc = 0.f;
#pragma unroll
    for (int c = 0; c < C_DIM; ++c)
      acc = fmaf(w1s[c * D_DIM + a], Ys[c * D_DIM + e], acc);
    M1[(size_t)b * 64 + threadIdx.x] = acc;
  }
}

// ---------------- register-resident 8x8 cyclic Jacobi ----------------
// All indices compile-time constant -> a[], u[] live in VGPRs.
__device__ __forceinline__ void jacobi8_reg(float a[64], float u[64]) {
#pragma unroll
  for (int i = 0; i < 64; ++i) u[i] = 0.f;
#pragma unroll
  for (int i = 0; i < 8; ++i) u[i * 8 + i] = 1.f;
#pragma unroll 1
  for (int sweep = 0; sweep < NSWEEP; ++sweep) {
#pragma unroll
    for (int p = 0; p < 7; ++p) {
#pragma unroll
      for (int q = p + 1; q < 8; ++q) {
        float app = a[p * 8 + p];
        float aqq = a[q * 8 + q];
        float apq = a[p * 8 + q];
        float taun = aqq - app;
        float t = (2.f * apq) * copysignf(1.f, taun) /
                  (fabsf(taun) + sqrtf(taun * taun + 4.f * apq * apq) + 1e-38f);
        float c = 1.f / sqrtf(1.f + t * t);
        float s = t * c;
        // rows p,q :  A <- J^T A
#pragma unroll
        for (int j = 0; j < 8; ++j) {
          float x = a[p * 8 + j], y = a[q * 8 + j];
          a[p * 8 + j] = c * x - s * y;
          a[q * 8 + j] = s * x + c * y;
        }
        // cols p,q :  A <- A J
#pragma unroll
        for (int i = 0; i < 8; ++i) {
          float x = a[i * 8 + p], y = a[i * 8 + q];
          a[i * 8 + p] = c * x - s * y;
          a[i * 8 + q] = s * x + c * y;
        }
        // U <- U J
#pragma unroll
        for (int i = 0; i < 8; ++i) {
          float x = u[i * 8 + p], y = u[i * 8 + q];
          u[i * 8 + p] = c * x - s * y;
          u[i * 8 + q] = s * x + c * y;
        }
      }
    }
  }
}

__global__ __launch_bounds__(64) void spd_eig_kernel(
    const float* __restrict__ M1, const float* __restrict__ w2,
    const float* __restrict__ fc, float* __restrict__ out) {
  __shared__ float w2s[64];
  __shared__ float fcs[128];
  const int lane = threadIdx.x;
  const int b = blockIdx.x * 64 + lane;
  w2s[lane] = w2[lane];
  fcs[lane] = fc[lane];
  fcs[lane + 64] = fc[lane + 64];
  __syncthreads();

  float a[64], u[64];
  // load M1[b] (per-thread contiguous, float4)
  const float4* m4 = (const float4*)(M1 + (size_t)b * 64);
#pragma unroll
  for (int i = 0; i < 16; ++i) {
    float4 v = m4[i];
    a[i * 4 + 0] = v.x; a[i * 4 + 1] = v.y;
    a[i * 4 + 2] = v.z; a[i * 4 + 3] = v.w;
  }

  // ---- eig 1 + rec (fused into M2 formation) ----
  jacobi8_reg(a, u);
  float wc[8];
#pragma unroll
  for (int k = 0; k < 8; ++k) wc[k] = fmaxf(a[k * 8 + k], EPSV);
  // V[k][e] = sum_i U[i][k] * w2[i][e]   (V = U^T w2), reuse a[]
  {
    float v[64];
#pragma unroll
    for (int k = 0; k < 8; ++k) {
#pragma unroll
      for (int e = 0; e < 8; ++e) {
        float acc = 0.f;
#pragma unroll
        for (int i = 0; i < 8; ++i)
          acc = fmaf(u[i * 8 + k], w2s[i * 8 + e], acc);
        v[k * 8 + e] = acc;
      }
    }
    // M2[aa][e] = sum_k V[k][aa] * wc[k] * V[k][e]  -> a[]
#pragma unroll
    for (int aa = 0; aa < 8; ++aa) {
#pragma unroll
      for (int e = 0; e < 8; ++e) {
        float acc = 0.f;
#pragma unroll
        for (int k = 0; k < 8; ++k)
          acc = fmaf(v[k * 8 + aa] * wc[k], v[k * 8 + e], acc);
        a[aa * 8 + e] = acc;
      }
    }
  }

  // ---- eig 2 + fused rec+logm ----
  jacobi8_reg(a, u);
  float lw[8];
#pragma unroll
  for (int k = 0; k < 8; ++k) lw[k] = logf(fmaxf(a[k * 8 + k], EPSV));

  // feat[i][j] = sum_k U[i][k] * lw[k] * U[j][k];  logits = feat @ fc
  float l0 = 0.f, l1 = 0.f;
  float* featg = out + 2 * (size_t)B_TOTAL + (size_t)b * 64;
#pragma unroll
  for (int i = 0; i < 8; ++i) {
    float row[8];
#pragma unroll
    for (int j = 0; j < 8; ++j) {
      float acc = 0.f;
#pragma unroll
      for (int k = 0; k < 8; ++k)
        acc = fmaf(u[i * 8 + k] * lw[k], u[j * 8 + k], acc);
      row[j] = acc;
      l0 = fmaf(acc, fcs[(i * 8 + j) * 2 + 0], l0);
      l1 = fmaf(acc, fcs[(i * 8 + j) * 2 + 1], l1);
    }
    float4* fo = (float4*)(featg + i * 8);
    fo[0] = make_float4(row[0], row[1], row[2], row[3]);
    fo[1] = make_float4(row[4], row[5], row[6], row[7]);
  }
  float mx = fmaxf(l0, l1);
  float lse = mx + logf(expf(l0 - mx) + expf(l1 - mx));
  out[(size_t)b * 2 + 0] = l0 - lse;
  out[(size_t)b * 2 + 1] = l1 - lse;
}

extern "C" void kernel_launch(void* const* d_in, const int* in_sizes, int n_in,
                              void* d_out, int out_size, void* d_ws, size_t ws_size,
                              hipStream_t stream) {
  const float* X  = (const float*)d_in[0];   // [8192,62,62]
  const float* w1 = (const float*)d_in[1];   // [62,8]
  const float* w2 = (const float*)d_in[2];   // [8,8]
  const float* fc = (const float*)d_in[3];   // [64,2]
  float* out = (float*)d_out;                // [8192*2] ++ [8192*64]
  float* M1 = (float*)d_ws;                  // 8192*64 floats = 2 MB

  bimap1_kernel<<<B_TOTAL, 256, 0, stream>>>(X, w1, M1);
  spd_eig_kernel<<<B_TOTAL / 64, 64, 0, stream>>>(M1, w2, fc, out);
}

// Round 3
// 74.400 us; speedup vs baseline: 5.3642x; 2.2172x over previous
//
#include <hip/hip_runtime.h>
#include <math.h>

#define B_TOTAL 8192
#define C_DIM 62
#define D_DIM 8
#define EPSV 1e-4f
#define NSWEEP 6

// ---------------- Kernel A: M1[b] = w1^T X[b] w1  (62->8) ----------------
__global__ __launch_bounds__(256) void bimap1_kernel(
    const float* __restrict__ X, const float* __restrict__ w1,
    float* __restrict__ M1) {
  __shared__ __align__(16) float Xs[C_DIM * C_DIM];   // 3844 floats
  __shared__ float w1s[C_DIM * D_DIM];                // 496
  __shared__ float Ys[C_DIM * D_DIM];
  const int b = blockIdx.x;
  // 3844 floats = 961 float4, and 3844*4B per batch keeps 16B alignment
  const float4* X4 = (const float4*)(X + (size_t)b * (C_DIM * C_DIM));
  float4* Xs4 = (float4*)Xs;
  for (int i = threadIdx.x; i < 961; i += 256) Xs4[i] = X4[i];
  for (int i = threadIdx.x; i < C_DIM * D_DIM; i += 256) w1s[i] = w1[i];
  __syncthreads();
  // Y[c][e] = sum_d X[c][d] * w1[d][e]
  for (int i = threadIdx.x; i < C_DIM * D_DIM; i += 256) {
    int c = i >> 3, e = i & 7;
    float acc = 0.f;
#pragma unroll
    for (int d = 0; d < C_DIM; ++d)
      acc = fmaf(Xs[c * C_DIM + d], w1s[d * D_DIM + e], acc);
    Ys[i] = acc;
  }
  __syncthreads();
  // M1[a][e] = sum_c w1[c][a] * Y[c][e]
  if (threadIdx.x < 64) {
    int a = threadIdx.x >> 3, e = threadIdx.x & 7;
    float acc = 0.f;
#pragma unroll
    for (int c = 0; c < C_DIM; ++c)
      acc = fmaf(w1s[c * D_DIM + a], Ys[c * D_DIM + e], acc);
    M1[(size_t)b * 64 + threadIdx.x] = acc;
  }
}

// ---------- 8-lane parallel 8x8 Jacobi (XOR tournament ordering) ----------
// Lane e of an 8-lane group owns column e of A and of U (8 regs each).
__device__ __forceinline__ float sel8(const float a[8], int e) {
  float t0 = (e & 4) ? a[4] : a[0];
  float t1 = (e & 4) ? a[5] : a[1];
  float t2 = (e & 4) ? a[6] : a[2];
  float t3 = (e & 4) ? a[7] : a[3];
  float u0 = (e & 2) ? t2 : t0;
  float u1 = (e & 2) ? t3 : t1;
  return (e & 1) ? u1 : u0;
}

__device__ __forceinline__ void jacobi8p(float a[8], float u[8],
                                         const int e, const int base) {
#pragma unroll
  for (int i = 0; i < 8; ++i) u[i] = (i == e) ? 1.f : 0.f;
#pragma unroll 1
  for (int sweep = 0; sweep < NSWEEP; ++sweep) {
#pragma unroll
    for (int m = 1; m < 8; ++m) {
      const int f = e ^ m;
      const bool lower = e < f;
      // own diagonal + off-diagonal of my pair
      float diag = sel8(a, e);
      float offd = sel8(a, f);
      // exchange columns (pre-update state) and pair scalars
      float aoth[8], uoth[8];
#pragma unroll
      for (int i = 0; i < 8; ++i) aoth[i] = __shfl_xor(a[i], m);
#pragma unroll
      for (int i = 0; i < 8; ++i) uoth[i] = __shfl_xor(u[i], m);
      float diag_o = __shfl_xor(diag, m);
      float offd_o = __shfl_xor(offd, m);
      // symmetrize apq so both lanes of the pair compute identical (c,s)
      float apq = 0.5f * (offd + offd_o);
      float app = lower ? diag : diag_o;
      float aqq = lower ? diag_o : diag;
      float taun = aqq - app;
      float t = (2.f * apq) * copysignf(1.f, taun) /
                (fabsf(taun) + sqrtf(fmaf(taun, taun, 4.f * apq * apq)) + 1e-38f);
      float c = rsqrtf(fmaf(t, t, 1.f));
      float s = t * c;
      float s2 = lower ? -s : s;
      // column update: A <- A J ; U <- U J  (own pair's rotation)
#pragma unroll
      for (int i = 0; i < 8; ++i) a[i] = fmaf(c, a[i], s2 * aoth[i]);
#pragma unroll
      for (int i = 0; i < 8; ++i) u[i] = fmaf(c, u[i], s2 * uoth[i]);
      // row update: A <- J^T A  (all 4 rotations, static pair indices)
#pragma unroll
      for (int i = 0; i < 8; ++i) {
        const int j = i ^ m;
        if (i < j) {
          float cr = __shfl(c, base | i);
          float sr = __shfl(s, base | i);
          float x = a[i], y = a[j];
          a[i] = fmaf(cr, x, -sr * y);
          a[j] = fmaf(sr, x, cr * y);
        }
      }
    }
  }
}

#define WSTRIDE 72  // floats per batch row-buffer; 72%8=0 (16B ok), 2-way banks

__global__ __launch_bounds__(256) void spd_eig8_kernel(
    const float* __restrict__ M1, const float* __restrict__ w2,
    const float* __restrict__ fc, float* __restrict__ out) {
  __shared__ __align__(16) float Wbuf[32 * WSTRIDE];  // per-batch 8x8 exchange
  __shared__ float lwbuf[32 * 8];
  __shared__ float w2s[64];
  __shared__ float fcs[128];
  const int tid = threadIdx.x;
  const int e = tid & 7;          // lane within batch group
  const int g = tid >> 3;         // batch group within block (0..31)
  const int base = tid & 56;      // wave-lane base of my group (for __shfl)
  const int b = blockIdx.x * 32 + g;
  if (tid < 64) w2s[tid] = w2[tid];
  else if (tid < 192) fcs[tid - 64] = fc[tid - 64];
  __syncthreads();

  // load column e of symmetric M1[b] ( = row e, contiguous )
  float a[8], u[8];
  const float4* m4 = (const float4*)(M1 + (size_t)b * 64 + e * 8);
  float4 v0 = m4[0], v1 = m4[1];
  a[0] = v0.x; a[1] = v0.y; a[2] = v0.z; a[3] = v0.w;
  a[4] = v1.x; a[5] = v1.y; a[6] = v1.z; a[7] = v1.w;

  // ---- eig 1 ----
  jacobi8p(a, u, e, base);
  float lam = sel8(a, e);
  float sw = sqrtf(fmaxf(lam, EPSV));
  // V[e][j] = sum_i U[i][e] * w2[i][j]  (row e of V = U^T w2), scaled by sqrt(wc)
  float v[8];
#pragma unroll
  for (int j = 0; j < 8; ++j) v[j] = 0.f;
#pragma unroll
  for (int i = 0; i < 8; ++i)
#pragma unroll
    for (int j = 0; j < 8; ++j) v[j] = fmaf(u[i], w2s[i * 8 + j], v[j]);
  float* Wg = &Wbuf[g * WSTRIDE];
#pragma unroll
  for (int j = 0; j < 8; ++j) Wg[e * 8 + j] = v[j] * sw;
  __syncthreads();
  // M2 column e: m2[i] = sum_k W[k][i] * W[k][e]
  float wcol[8];
#pragma unroll
  for (int k = 0; k < 8; ++k) wcol[k] = Wg[k * 8 + e];
  float m2[8];
#pragma unroll
  for (int i = 0; i < 8; ++i) m2[i] = 0.f;
#pragma unroll
  for (int k = 0; k < 8; ++k) {
    float4 r0 = *(const float4*)&Wg[k * 8 + 0];
    float4 r1 = *(const float4*)&Wg[k * 8 + 4];
    m2[0] = fmaf(r0.x, wcol[k], m2[0]); m2[1] = fmaf(r0.y, wcol[k], m2[1]);
    m2[2] = fmaf(r0.z, wcol[k], m2[2]); m2[3] = fmaf(r0.w, wcol[k], m2[3]);
    m2[4] = fmaf(r1.x, wcol[k], m2[4]); m2[5] = fmaf(r1.y, wcol[k], m2[5]);
    m2[6] = fmaf(r1.z, wcol[k], m2[6]); m2[7] = fmaf(r1.w, wcol[k], m2[7]);
  }
  __syncthreads();   // all reads of Wbuf done before reuse below

  // ---- eig 2 + rec+logm fused ----
#pragma unroll
  for (int i = 0; i < 8; ++i) a[i] = m2[i];
  jacobi8p(a, u, e, base);
  float lw = logf(fmaxf(sel8(a, e), EPSV));
  // T[k][i] = U[i][k]; lane e holds row e of T (=u[]). Share via LDS.
#pragma unroll
  for (int i = 0; i < 8; ++i) Wg[e * 8 + i] = u[i];
  lwbuf[g * 8 + e] = lw;
  __syncthreads();
  // feat column e: fcol[i] = sum_k lw_k * T[k][i] * T[k][e]
  float mk[8];
#pragma unroll
  for (int k = 0; k < 8; ++k) mk[k] = lwbuf[g * 8 + k] * Wg[k * 8 + e];
  float fcol[8];
#pragma unroll
  for (int i = 0; i < 8; ++i) fcol[i] = 0.f;
#pragma unroll
  for (int k = 0; k < 8; ++k) {
    float4 r0 = *(const float4*)&Wg[k * 8 + 0];
    float4 r1 = *(const float4*)&Wg[k * 8 + 4];
    fcol[0] = fmaf(r0.x, mk[k], fcol[0]); fcol[1] = fmaf(r0.y, mk[k], fcol[1]);
    fcol[2] = fmaf(r0.z, mk[k], fcol[2]); fcol[3] = fmaf(r0.w, mk[k], fcol[3]);
    fcol[4] = fmaf(r1.x, mk[k], fcol[4]); fcol[5] = fmaf(r1.y, mk[k], fcol[5]);
    fcol[6] = fmaf(r1.z, mk[k], fcol[6]); fcol[7] = fmaf(r1.w, mk[k], fcol[7]);
  }
  // store feat column e + partial logits
  float l0 = 0.f, l1 = 0.f;
  float* featg = out + 2 * (size_t)B_TOTAL + (size_t)b * 64;
#pragma unroll
  for (int i = 0; i < 8; ++i) {
    featg[i * 8 + e] = fcol[i];
    l0 = fmaf(fcol[i], fcs[(i * 8 + e) * 2 + 0], l0);
    l1 = fmaf(fcol[i], fcs[(i * 8 + e) * 2 + 1], l1);
  }
  // reduce logits over the 8-lane group
#pragma unroll
  for (int mm = 1; mm < 8; mm <<= 1) {
    l0 += __shfl_xor(l0, mm);
    l1 += __shfl_xor(l1, mm);
  }
  float mx = fmaxf(l0, l1);
  float lse = mx + logf(expf(l0 - mx) + expf(l1 - mx));
  if (e < 2) out[(size_t)b * 2 + e] = (e ? l1 : l0) - lse;
}

extern "C" void kernel_launch(void* const* d_in, const int* in_sizes, int n_in,
                              void* d_out, int out_size, void* d_ws, size_t ws_size,
                              hipStream_t stream) {
  const float* X  = (const float*)d_in[0];   // [8192,62,62]
  const float* w1 = (const float*)d_in[1];   // [62,8]
  const float* w2 = (const float*)d_in[2];   // [8,8]
  const float* fc = (const float*)d_in[3];   // [64,2]
  float* out = (float*)d_out;                // [8192*2] ++ [8192*64]
  float* M1 = (float*)d_ws;                  // 8192*64 floats = 2 MB

  bimap1_kernel<<<B_TOTAL, 256, 0, stream>>>(X, w1, M1);
  spd_eig8_kernel<<<B_TOTAL / 32, 256, 0, stream>>>(M1, w2, fc, out);
}